// Round 10
// baseline (127.057 us; speedup 1.0000x reference)
//
#include <hip/hip_runtime.h>

typedef __attribute__((ext_vector_type(8))) short short8;   // 8 bf16 (MFMA A/B frag)
typedef __attribute__((ext_vector_type(4))) float f32x4;

#define SDIM 32
#define HDIM 34
#define NEXP 12
#define ACOL 256
#define SPB  256
#define ROWS 448           // per-block padded row window (max 436)

// fp32 -> bf16 (round-to-nearest-ish), pack two into one dword
__device__ __forceinline__ unsigned int bpack(float lo, float hi) {
    unsigned int a = __builtin_bit_cast(unsigned int, lo);
    unsigned int b = __builtin_bit_cast(unsigned int, hi);
    return ((a + 0x8000u) >> 16) | ((b + 0x8000u) & 0xffff0000u);
}

// ---- k0: pack Wout into fragment-ordered bf16 records ----
// wpack[((e*4+wv)*4+j)*64 + lane] = 8 bf16 of W[col=wv*64+j*16+(lane&15)][k=8g..8g+7]
__global__ __launch_bounds__(256) void k0_wpack(
    const float* __restrict__ Wout, uint4* __restrict__ wpack,
    unsigned int* __restrict__ w2p)
{
    const int tid = blockIdx.x * 256 + threadIdx.x;
    if (tid >= NEXP * 4 * 4 * 64) return;
    const int lane = tid & 63;
    const int j    = (tid >> 6) & 3;
    const int wvv  = (tid >> 8) & 3;
    const int e    = tid >> 10;
    const int r = lane & 15, g = lane >> 4;
    const int col = wvv * 64 + j * 16 + r;
    const float* wr = Wout + ((size_t)e * ACOL + col) * HDIM;
    uint4 q;
    q.x = bpack(wr[g*8+0], wr[g*8+1]);
    q.y = bpack(wr[g*8+2], wr[g*8+3]);
    q.z = bpack(wr[g*8+4], wr[g*8+5]);
    q.w = bpack(wr[g*8+6], wr[g*8+7]);
    wpack[tid] = q;
    if (tid < NEXP * ACOL) {                       // w2: k=32,33 per (e,col)
        const float* wr2 = Wout + (size_t)tid * HDIM;
        w2p[tid] = bpack(wr2[32], wr2[33]);
    }
}

// ---- K3: trunk GEMV + block-local expert sort; write x-rows to global window ----
__global__ __launch_bounds__(256, 4) void k3_trunk(
    const float* __restrict__ states, const int* __restrict__ epoch_idx,
    const float* __restrict__ W1, const float* __restrict__ b1,
    uint4* __restrict__ xg, unsigned int* __restrict__ xtg,
    unsigned short* __restrict__ ridg, int* __restrict__ meta, int nB)
{
    __shared__ float w1s[HDIM * SDIM];
    __shared__ float b1s[HDIM];
    __shared__ int cnt[NEXP], goff[NEXP];

    const int t = threadIdx.x;
    const int b = blockIdx.x;
    for (int i = t; i < HDIM * SDIM; i += 256) w1s[i] = W1[i];
    if (t < HDIM) b1s[t] = b1[t];
    if (t < NEXP) cnt[t] = 0;

    const int  sidx  = b * SPB + t;
    const bool valid = (sidx < nB);
    float sr[SDIM];
    int e = 0;
    if (valid) {
        const f32x4* sp = (const f32x4*)(states + (size_t)sidx * SDIM);
        #pragma unroll
        for (int q = 0; q < SDIM / 4; ++q) {
            f32x4 v = sp[q];
            sr[4*q+0] = v[0]; sr[4*q+1] = v[1]; sr[4*q+2] = v[2]; sr[4*q+3] = v[3];
        }
        e = epoch_idx[sidx];
    }
    __syncthreads();                 // cnt zeroed, w1s staged

    int rank = 0;
    if (valid) rank = atomicAdd(&cnt[e], 1);
    __syncthreads();                 // cnt final

    if (t == 0) {
        int base = 0;
        #pragma unroll
        for (int i = 0; i < NEXP; ++i) {
            goff[i] = base;
            base += ((cnt[i] + 15) >> 4) << 4;
        }
    }
    float x[HDIM];
    if (valid) {
        #pragma unroll 2
        for (int h = 0; h < HDIM; ++h) {
            float acc = b1s[h];
            const float4* wr = (const float4*)(w1s + h * SDIM);
            #pragma unroll
            for (int q = 0; q < SDIM / 4; ++q) {
                float4 wv = wr[q];
                acc = fmaf(sr[4*q+0], wv.x, acc);
                acc = fmaf(sr[4*q+1], wv.y, acc);
                acc = fmaf(sr[4*q+2], wv.z, acc);
                acc = fmaf(sr[4*q+3], wv.w, acc);
            }
            x[h] = fmaxf(acc, 0.0f);
        }
    }
    __syncthreads();                 // goff ready

    if (valid) {
        const int slot = goff[e] + rank;
        unsigned d[17];
        #pragma unroll
        for (int k = 0; k < 17; ++k) d[k] = bpack(x[2*k], x[2*k+1]);
        uint4* xr = xg + ((size_t)b * ROWS + slot) * 4;
        xr[0] = make_uint4(d[0],  d[1],  d[2],  d[3]);
        xr[1] = make_uint4(d[4],  d[5],  d[6],  d[7]);
        xr[2] = make_uint4(d[8],  d[9],  d[10], d[11]);
        xr[3] = make_uint4(d[12], d[13], d[14], d[15]);
        xtg[b * ROWS + slot]  = d[16];
        ridg[b * ROWS + slot] = (unsigned short)t;
    }
    if (t < NEXP) {
        meta[b * 24 + t]        = goff[t];
        meta[b * 24 + NEXP + t] = cnt[t];
    }
}

// ---- K4: barrier-free dense GEMM over the block's sorted window ----
__global__ __launch_bounds__(256, 4) void k4_gemm(
    const uint4* __restrict__ wpack, const unsigned int* __restrict__ w2p,
    const float* __restrict__ bout, const int* __restrict__ mask,
    const uint4* __restrict__ xg, const unsigned int* __restrict__ xtg,
    const unsigned short* __restrict__ ridg, const int* __restrict__ meta,
    float* __restrict__ out)
{
    __shared__ float slab[4][16 * 68];     // private per-wave transpose slabs
    __shared__ unsigned short lrid[ROWS];
    __shared__ int lgoff[NEXP], lcnt[NEXP];

    const int t = threadIdx.x;
    const int b = blockIdx.x;

    if (t < NEXP) {
        lgoff[t] = meta[b * 24 + t];
        lcnt[t]  = meta[b * 24 + NEXP + t];
    }
    {   // stage rowid table (896 B) into LDS
        const uint* rsrc = (const uint*)(ridg + b * ROWS);
        uint* rdst = (uint*)lrid;
        if (t < ROWS / 2) rdst[t] = rsrc[t];
    }
    __syncthreads();                       // ONLY barrier in this kernel

    const int wv = t >> 6, lane = t & 63;
    const int r = lane & 15, g = lane >> 4;
    const int m = mask[wv * 64 + lane];
    const float NEG = -1e9f;
    const int s0 = b * SPB;
    float* mystg = slab[wv];
    const uint4*        xb  = xg  + ((size_t)b * ROWS) * 4;
    const unsigned int* xtb = xtg + b * ROWS;

    for (int e2 = 0; e2 < NEXP; ++e2) {
        const int nv = lcnt[e2];
        if (nv == 0) continue;
        const int ntiles = (nv + 15) >> 4;
        const int tb = lgoff[e2];

        // coalesced W fragments for this wave's 64-action strip
        short8   bf1[4];
        unsigned w2[4];
        float    bias[4];
        const uint4* wp = wpack + ((size_t)(e2 * 4 + wv) * 4) * 64 + lane;
        #pragma unroll
        for (int j = 0; j < 4; ++j) {
            bf1[j]  = __builtin_bit_cast(short8, wp[j * 64]);
            w2[j]   = (g == 0) ? w2p[e2 * ACOL + wv * 64 + j * 16 + r] : 0u;
            bias[j] = bout[e2 * ACOL + wv * 64 + j * 16 + r];
        }

        for (int st = 0; st < ntiles; ++st) {
            const int rb  = tb + (st << 4);
            const int row = rb + r;
            short8 a1 = __builtin_bit_cast(short8, xb[row * 4 + g]);  // 1KB/tile
            short8 a2 = __builtin_bit_cast(short8,
                          make_uint4(g == 0 ? xtb[row] : 0u, 0u, 0u, 0u));

            #pragma unroll
            for (int j = 0; j < 4; ++j) {
                f32x4 a = {bias[j], bias[j], bias[j], bias[j]};
                a = __builtin_amdgcn_mfma_f32_16x16x32_bf16(a1, bf1[j], a, 0, 0, 0);
                short8 b2 = __builtin_bit_cast(short8, make_uint4(w2[j], 0u, 0u, 0u));
                a = __builtin_amdgcn_mfma_f32_16x16x32_bf16(a2, b2, a, 0, 0, 0);
                #pragma unroll
                for (int i = 0; i < 4; ++i)
                    mystg[(4 * g + i) * 68 + 16 * j + r] = a[i];  // 2-way banks
            }

            const int nrow = nv - (st << 4);
            #pragma unroll
            for (int lrow = 0; lrow < 16; ++lrow) {
                if (lrow < nrow) {
                    const int rid = lrid[rb + lrow];              // uniform
                    float v = mystg[lrow * 68 + lane];
                    v = m ? v : NEG;
                    out[(size_t)(s0 + rid) * ACOL + wv * 64 + lane] = v;  // 256B/instr
                }
            }
        }
    }
}

extern "C" void kernel_launch(void* const* d_in, const int* in_sizes, int n_in,
                              void* d_out, int out_size, void* d_ws, size_t ws_size,
                              hipStream_t stream) {
    const float* states    = (const float*)d_in[0];
    const int*   epoch_idx = (const int*)  d_in[1];
    const float* W1        = (const float*)d_in[2];
    const float* b1        = (const float*)d_in[3];
    const float* Wout      = (const float*)d_in[4];
    const float* bout      = (const float*)d_in[5];
    const int*   mask      = (const int*)  d_in[6];
    float*       out       = (float*)d_out;

    const int nB   = in_sizes[0] / SDIM;
    const int nblk = (nB + SPB - 1) / SPB;

    char* ws = (char*)d_ws;
    size_t o = 0;
    uint4*          wpack = (uint4*)(ws + o);        o += 196608;
    unsigned int*   w2p   = (unsigned int*)(ws + o); o += 12288;
    int*            meta  = (int*)(ws + o);          o += (size_t)nblk * 24 * 4;
    o = (o + 255) & ~(size_t)255;
    unsigned short* ridg  = (unsigned short*)(ws + o); o += (size_t)nblk * ROWS * 2;
    o = (o + 255) & ~(size_t)255;
    unsigned int*   xtg   = (unsigned int*)(ws + o); o += (size_t)nblk * ROWS * 4;
    o = (o + 255) & ~(size_t)255;
    uint4*          xg    = (uint4*)(ws + o);        // nblk * ROWS * 64 B

    k0_wpack<<<48, 256, 0, stream>>>(Wout, wpack, w2p);
    k3_trunk<<<nblk, 256, 0, stream>>>(states, epoch_idx, W1, b1,
                                       xg, xtg, ridg, meta, nB);
    k4_gemm<<<nblk, 256, 0, stream>>>(wpack, w2p, bout, mask,
                                      xg, xtg, ridg, meta, out);
}